// Round 9
// baseline (79.490 us; speedup 1.0000x reference)
//
#include <hip/hip_runtime.h>
#include <hip/hip_bf16.h>

// Problem constants
#define B_ROWS 65536
#define DIN    784
#define DHID   100
#define DOUT   10

#define NP     112                 // DHID padded to 7*16
#define NT     27                  // k-steps of 32 (864; slots 784.. are zero pad)
#define W1T_ELEMS (NT * 7 * 512)   // 96768 bf16, fragment-order layout
#define W2T_OFF   W1T_ELEMS        // w2t: [16][128] bf16 = 2048
#define WBUF_ELEMS (W1T_ELEMS + 2048)
#define PART_OFF  ((((WBUF_ELEMS * 2) + 255) & ~255))   // byte offset of freq partials
#define TM     256                 // rows per block (4 waves x 64 rows)
#define GRID1  (B_ROWS / TM)       // 256 -> 1 block/CU, 1 wave/SIMD
#define PART_BYTES (GRID1 * NP * 4)
#define CNT_OFF   (PART_OFF + PART_BYTES)

typedef float  f32x4  __attribute__((ext_vector_type(4)));
typedef __bf16 bf16x8 __attribute__((ext_vector_type(8)));

__device__ inline unsigned short f2bf(float f) {
    unsigned int u = __builtin_bit_cast(unsigned int, f);
    u = (u + 0x7fffu + ((u >> 16) & 1u)) >> 16;   // RNE
    return (unsigned short)u;
}

// ---- prep: build fragment-order W1T + W2T (bf16, zero-padded); zero done-counter.
// W1T: idx = ((t*7+n)*64 + lane)*8 + j holds W1[k = t*32+(lane>>4)*8+j][col = n*16+(lane&15)]
__global__ void prep_kernel(const float* __restrict__ W1,
                            const float* __restrict__ W2,
                            unsigned short* __restrict__ wbuf,
                            unsigned* __restrict__ done) {
    int idx = blockIdx.x * 256 + threadIdx.x;
    if (idx == 0) *done = 0u;                    // reset per call (graph-replay safe)
    if (idx < W1T_ELEMS) {
        int s  = idx >> 9;          // fragment slot (t*7+n)
        int e  = idx & 511;
        int ln = e >> 3, j = e & 7;
        int n  = s % 7, t = s / 7;
        int k   = t * 32 + ((ln >> 4) << 3) + j;
        int col = n * 16 + (ln & 15);
        float v = (k < DIN && col < DHID) ? W1[k * DHID + col] : 0.f;
        wbuf[idx] = f2bf(v);
    } else if (idx < WBUF_ELEMS) {
        int j2 = idx - W1T_ELEMS;
        int r  = j2 >> 7;           // 0..15 (output col)
        int k  = j2 & 127;          // 0..127 (h col)
        float v = (r < DOUT && k < DHID) ? W2[k * DOUT + r] : 0.f;
        wbuf[idx] = f2bf(v);
    }
}

#define LOADX4(dst, kk)                                                         \
    do {                                                                        \
        _Pragma("unroll")                                                       \
        for (int m = 0; m < 4; ++m) {                                           \
            dst[m][0] = *(const float4*)(xp[m] + (kk));                         \
            dst[m][1] = *(const float4*)(xp[m] + (kk) + 4);                     \
        }                                                                       \
    } while (0)

#define ZEROX4(dst)                                                             \
    do {                                                                        \
        _Pragma("unroll")                                                       \
        for (int m = 0; m < 4; ++m)                                             \
            dst[m][0] = dst[m][1] = make_float4(0.f, 0.f, 0.f, 0.f);            \
    } while (0)

#define CVT_MFMA4(xc, bsrc)                                                     \
    do {                                                                        \
        bf16x8 av[4];                                                           \
        _Pragma("unroll")                                                       \
        for (int m = 0; m < 4; ++m) {                                           \
            av[m][0] = (__bf16)xc[m][0].x; av[m][1] = (__bf16)xc[m][0].y;       \
            av[m][2] = (__bf16)xc[m][0].z; av[m][3] = (__bf16)xc[m][0].w;       \
            av[m][4] = (__bf16)xc[m][1].x; av[m][5] = (__bf16)xc[m][1].y;       \
            av[m][6] = (__bf16)xc[m][1].z; av[m][7] = (__bf16)xc[m][1].w;       \
        }                                                                       \
        _Pragma("unroll")                                                       \
        for (int n = 0; n < 7; ++n)                                             \
            _Pragma("unroll")                                                   \
            for (int m = 0; m < 4; ++m)                                         \
                acc[m][n] = __builtin_amdgcn_mfma_f32_16x16x32_bf16(            \
                    av[m], bsrc[n], acc[m][n], 0, 0, 0);                        \
    } while (0)

// one pipeline phase: consume (xs,bs) for k-step t; refill slot with t+3
#define PHASE(xs, bs, t)                                                        \
    do {                                                                        \
        float4 xn[4][2];                                                        \
        const int kk = ((t) + 3) * 32 + q * 8;                                  \
        if (kk + 8 <= DIN) LOADX4(xn, kk); else ZEROX4(xn);                     \
        const int tb = ((t) + 3 < NT) ? (t) + 3 : NT - 1;                       \
        const unsigned short* wp = wb + tb * (7 * 512);                         \
        bf16x8 bn[7];                                                           \
        _Pragma("unroll")                                                       \
        for (int n = 0; n < 7; ++n) bn[n] = *(const bf16x8*)(wp + n * 512);     \
        CVT_MFMA4(xs, bs);                                                      \
        _Pragma("unroll")                                                       \
        for (int m = 0; m < 4; ++m) { xs[m][0] = xn[m][0]; xs[m][1] = xn[m][1]; } \
        _Pragma("unroll")                                                       \
        for (int n = 0; n < 7; ++n) bs[n] = bn[n];                              \
    } while (0)

__global__ __launch_bounds__(256, 1)
void fused_mlp8(const float* __restrict__ x,
                const unsigned short* __restrict__ wbuf,
                const float* __restrict__ b1,
                const float* __restrict__ b2,
                const float* __restrict__ freq_in,
                float* __restrict__ outp,
                float* __restrict__ freq_out,
                float* __restrict__ part,
                unsigned* __restrict__ done) {
    __shared__ unsigned short hs[TM][128];   // 64 KB bf16 h tile (cols 112..127 zeroed)
    __shared__ float logits[TM][16];         // 16 KB; reused: freq scratch then logits
    __shared__ float red[2][NP];             // last-block reduction scratch
    __shared__ int lastFlag;

    const int tid  = threadIdx.x;
    const int lane = tid & 63;
    const int wave = tid >> 6;       // 0..3, owns rows wave*64 .. +63
    const int r16  = lane & 15;
    const int q    = lane >> 4;      // 0..3

    const float* xp[4];
    #pragma unroll
    for (int m = 0; m < 4; ++m)
        xp[m] = x + ((size_t)blockIdx.x * TM + wave * 64 + m * 16 + r16) * DIN;
    const unsigned short* wb = wbuf + lane * 8;

    // ---- GEMM1: 64 rows/wave, x and B both pipelined 3 deep (static 3-slot rotation)
    f32x4 acc[4][7] = {};
    float4 xs0[4][2], xs1[4][2], xs2[4][2];
    bf16x8 bs0[7], bs1[7], bs2[7];
    {
        LOADX4(xs0, 0 * 32 + q * 8);
        LOADX4(xs1, 1 * 32 + q * 8);
        LOADX4(xs2, 2 * 32 + q * 8);
        #pragma unroll
        for (int n = 0; n < 7; ++n) {
            bs0[n] = *(const bf16x8*)(wb + 0 * 3584 + n * 512);
            bs1[n] = *(const bf16x8*)(wb + 1 * 3584 + n * 512);
            bs2[n] = *(const bf16x8*)(wb + 2 * 3584 + n * 512);
        }
    }
    #pragma unroll 1
    for (int tt = 0; tt < NT / 3; ++tt) {
        const int t = tt * 3;
        PHASE(xs0, bs0, t);
        PHASE(xs1, bs1, t + 1);
        PHASE(xs2, bs2, t + 2);
    }

    // ---- zero-pad hs cols 112..127 (GEMM2 reads them; avoid NaN garbage)
    {
        uint4 z; z.x = z.y = z.z = z.w = 0;
        *(uint4*)&hs[tid][112] = z;
        *(uint4*)&hs[tid][120] = z;
    }

    // ---- bias + relu -> hs (bf16); freq partial from registers (no atomics)
    const bool lastBlk = (blockIdx.x == GRID1 - 1);
    #pragma unroll
    for (int n = 0; n < 7; ++n) {
        const int col = n * 16 + r16;
        const float bias = (col < DHID) ? b1[col] : 0.f;
        float cnt = 0.f;
        #pragma unroll
        for (int m = 0; m < 4; ++m)
            #pragma unroll
            for (int i = 0; i < 4; ++i) {
                float v = acc[m][n][i] + bias;
                v = v > 0.f ? v : 0.f;
                union { __bf16 h; unsigned short u; } cv;
                cv.h = (__bf16)v;
                hs[wave * 64 + m * 16 + q * 4 + i][col] = cv.u;
                // reference skips the globally-last row (65535)
                bool excl = lastBlk && (wave == 3) && (m == 3) && (q == 3) && (i == 3);
                cnt += (v > 0.f && !excl) ? 1.f : 0.f;
            }
        cnt += __shfl_xor(cnt, 16);   // reduce over q (lane = q*16 + r16)
        cnt += __shfl_xor(cnt, 32);
        if (q == 0) ((float*)logits)[wave * NP + col] = cnt;  // flat < 448, disjoint
    }
    __syncthreads();
    if (tid < NP) {
        float s = ((float*)logits)[0 * NP + tid] + ((float*)logits)[1 * NP + tid]
                + ((float*)logits)[2 * NP + tid] + ((float*)logits)[3 * NP + tid];
        part[(size_t)blockIdx.x * NP + tid] = s;
    }
    __syncthreads();   // logits scratch free before GEMM2 reuses it

    // ---- GEMM2 via MFMA: logits[256][16] = hs[256][128] @ w2t^T, K=128
    const unsigned short* w2t = wbuf + W2T_OFF;
    bf16x8 bv2[4];
    #pragma unroll
    for (int ks = 0; ks < 4; ++ks)
        bv2[ks] = *(const bf16x8*)(w2t + r16 * 128 + ks * 32 + q * 8);
    f32x4 acc2[4] = {};
    #pragma unroll
    for (int m = 0; m < 4; ++m)
        #pragma unroll
        for (int ks = 0; ks < 4; ++ks) {
            bf16x8 a2 = *(const bf16x8*)&hs[wave * 64 + m * 16 + r16][ks * 32 + q * 8];
            acc2[m] = __builtin_amdgcn_mfma_f32_16x16x32_bf16(a2, bv2[ks], acc2[m], 0, 0, 0);
        }
    const float bias2 = (r16 < DOUT) ? b2[r16] : 0.f;
    #pragma unroll
    for (int m = 0; m < 4; ++m)
        #pragma unroll
        for (int i = 0; i < 4; ++i)
            logits[wave * 64 + m * 16 + q * 4 + i][r16] = acc2[m][i] + bias2;
    __syncthreads();

    // ---- softmax: one thread per row (all 256 threads active)
    {
        float lg[DOUT];
        #pragma unroll
        for (int k = 0; k < DOUT; ++k) lg[k] = logits[tid][k];
        float mx = lg[0];
        #pragma unroll
        for (int k = 1; k < DOUT; ++k) mx = fmaxf(mx, lg[k]);
        float s = 0.f;
        #pragma unroll
        for (int k = 0; k < DOUT; ++k) { lg[k] = __expf(lg[k] - mx); s += lg[k]; }
        float inv = 1.f / s;
        float* o = outp + ((size_t)blockIdx.x * TM + tid) * DOUT;
        #pragma unroll
        for (int k = 0; k < DOUT; ++k) o[k] = lg[k] * inv;
    }

    // ---- completion counter: last block reduces part -> freq_out (no extra kernel)
    __threadfence();                                   // release part writes, device scope
    if (tid == 0) {
        unsigned old = atomicAdd(done, 1u);            // device-scope by default
        lastFlag = (old == GRID1 - 1) ? 1 : 0;
    }
    __syncthreads();
    if (lastFlag) {
        __threadfence();                               // acquire other blocks' part writes
        // 224 threads: col = tid%112, half = tid/112; each sums 128 blocks.
        if (tid < 2 * NP) {
            const int col  = tid % NP;
            const int half = tid / NP;
            const int b0   = half * (GRID1 / 2);
            float s0 = 0.f, s1 = 0.f, s2 = 0.f, s3 = 0.f;
            #pragma unroll 4
            for (int b = 0; b < GRID1 / 2; b += 4) {
                s0 += part[(size_t)(b0 + b + 0) * NP + col];
                s1 += part[(size_t)(b0 + b + 1) * NP + col];
                s2 += part[(size_t)(b0 + b + 2) * NP + col];
                s3 += part[(size_t)(b0 + b + 3) * NP + col];
            }
            red[half][col] = ((s0 + s1) + (s2 + s3));
        }
        __syncthreads();
        if (tid < DHID)
            freq_out[tid] = freq_in[tid] + (red[0][tid] + red[1][tid]);
    }
}

extern "C" void kernel_launch(void* const* d_in, const int* in_sizes, int n_in,
                              void* d_out, int out_size, void* d_ws, size_t ws_size,
                              hipStream_t stream) {
    const float* x    = (const float*)d_in[0];
    const float* W1   = (const float*)d_in[1];
    const float* b1   = (const float*)d_in[2];
    const float* freq = (const float*)d_in[3];
    const float* W2   = (const float*)d_in[4];
    const float* b2   = (const float*)d_in[5];
    float* outp     = (float*)d_out;
    float* freq_out = outp + (size_t)B_ROWS * DOUT;
    unsigned short* wbuf = (unsigned short*)d_ws;
    float* part     = (float*)((char*)d_ws + PART_OFF);   // 256*112*4 = 115 KB
    unsigned* done  = (unsigned*)((char*)d_ws + CNT_OFF);

    prep_kernel<<<(WBUF_ELEMS + 255) / 256, 256, 0, stream>>>(W1, W2, wbuf, done);
    fused_mlp8<<<GRID1, 256, 0, stream>>>(x, wbuf, b1, b2, freq, outp, freq_out, part, done);
}

// Round 10
// 78.390 us; speedup vs baseline: 1.0140x; 1.0140x over previous
//
#include <hip/hip_runtime.h>
#include <hip/hip_bf16.h>

// Problem constants
#define B_ROWS 65536
#define DIN    784
#define DHID   100
#define DOUT   10

#define NP     112                 // DHID padded to 7*16
#define NT     26                  // k-steps of 32 (832; slots 784.. are zero pad)
#define W1T_ELEMS (NT * 7 * 512)   // 93184 bf16, fragment-order layout
#define W2T_OFF   W1T_ELEMS        // w2t: [16][128] bf16 = 2048
#define WBUF_ELEMS (W1T_ELEMS + 2048)
#define PART_OFF  ((((WBUF_ELEMS * 2) + 255) & ~255))   // byte offset of freq partials
#define TM     256                 // rows per block (4 waves x 64 rows)
#define GRID1  (B_ROWS / TM)       // 256 -> 1 block/CU, 1 wave/SIMD
#define PART_BYTES (GRID1 * NP * 4)
#define CNT_OFF   (PART_OFF + PART_BYTES)

typedef float  f32x4  __attribute__((ext_vector_type(4)));
typedef __bf16 bf16x8 __attribute__((ext_vector_type(8)));

__device__ inline unsigned short f2bf(float f) {
    unsigned int u = __builtin_bit_cast(unsigned int, f);
    u = (u + 0x7fffu + ((u >> 16) & 1u)) >> 16;   // RNE
    return (unsigned short)u;
}

// ---- prep: build fragment-order W1T + W2T (bf16, zero-padded); zero done-counter.
// W1T: idx = ((t*7+n)*64 + lane)*8 + j holds W1[k = t*32+(lane>>4)*8+j][col = n*16+(lane&15)]
__global__ void prep_kernel(const float* __restrict__ W1,
                            const float* __restrict__ W2,
                            unsigned short* __restrict__ wbuf,
                            unsigned* __restrict__ done) {
    int idx = blockIdx.x * 256 + threadIdx.x;
    if (idx == 0) *done = 0u;                    // reset per call (graph-replay safe)
    if (idx < W1T_ELEMS) {
        int s  = idx >> 9;          // fragment slot (t*7+n)
        int e  = idx & 511;
        int ln = e >> 3, j = e & 7;
        int n  = s % 7, t = s / 7;
        int k   = t * 32 + ((ln >> 4) << 3) + j;
        int col = n * 16 + (ln & 15);
        float v = (k < DIN && col < DHID) ? W1[k * DHID + col] : 0.f;
        wbuf[idx] = f2bf(v);
    } else if (idx < WBUF_ELEMS) {
        int j2 = idx - W1T_ELEMS;
        int r  = j2 >> 7;           // 0..15 (output col)
        int k  = j2 & 127;          // 0..127 (h col)
        float v = (r < DOUT && k < DHID) ? W2[k * DOUT + r] : 0.f;
        wbuf[idx] = f2bf(v);
    }
}

#define LOADX4(dst, kk)                                                         \
    do {                                                                        \
        _Pragma("unroll")                                                       \
        for (int m = 0; m < 4; ++m) {                                           \
            dst[m][0] = *(const float4*)(xp[m] + (kk));                         \
            dst[m][1] = *(const float4*)(xp[m] + (kk) + 4);                     \
        }                                                                       \
    } while (0)

#define ZEROX4(dst)                                                             \
    do {                                                                        \
        _Pragma("unroll")                                                       \
        for (int m = 0; m < 4; ++m)                                             \
            dst[m][0] = dst[m][1] = make_float4(0.f, 0.f, 0.f, 0.f);            \
    } while (0)

#define CVT_MFMA4(xc, bsrc)                                                     \
    do {                                                                        \
        bf16x8 av[4];                                                           \
        _Pragma("unroll")                                                       \
        for (int m = 0; m < 4; ++m) {                                           \
            av[m][0] = (__bf16)xc[m][0].x; av[m][1] = (__bf16)xc[m][0].y;       \
            av[m][2] = (__bf16)xc[m][0].z; av[m][3] = (__bf16)xc[m][0].w;       \
            av[m][4] = (__bf16)xc[m][1].x; av[m][5] = (__bf16)xc[m][1].y;       \
            av[m][6] = (__bf16)xc[m][1].z; av[m][7] = (__bf16)xc[m][1].w;       \
        }                                                                       \
        _Pragma("unroll")                                                       \
        for (int n = 0; n < 7; ++n)                                             \
            _Pragma("unroll")                                                   \
            for (int m = 0; m < 4; ++m)                                         \
                acc[m][n] = __builtin_amdgcn_mfma_f32_16x16x32_bf16(            \
                    av[m], bsrc[n], acc[m][n], 0, 0, 0);                        \
    } while (0)

__global__ __launch_bounds__(256, 1)
void fused_mlp9(const float* __restrict__ x,
                const unsigned short* __restrict__ wbuf,
                const float* __restrict__ b1,
                const float* __restrict__ b2,
                const float* __restrict__ freq_in,
                float* __restrict__ outp,
                float* __restrict__ freq_out,
                float* __restrict__ part,
                unsigned* __restrict__ done) {
    __shared__ unsigned short hs[TM][128];   // 64 KB bf16 h tile (cols 112..127 zeroed)
    __shared__ float logits[TM][16];         // 16 KB; reused: freq scratch then logits
    __shared__ float red[2][NP];             // last-block reduction scratch
    __shared__ int lastFlag;

    const int tid  = threadIdx.x;
    const int lane = tid & 63;
    const int wave = tid >> 6;       // 0..3, owns rows wave*64 .. +63
    const int r16  = lane & 15;
    const int q    = lane >> 4;      // 0..3

    const float* xp[4];
    #pragma unroll
    for (int m = 0; m < 4; ++m)
        xp[m] = x + ((size_t)blockIdx.x * TM + wave * 64 + m * 16 + r16) * DIN;
    const unsigned short* wb = wbuf + lane * 8;

    // ---- GEMM1: 64 rows/wave (4 A-frags share each B-frag), x 2-deep, B 1-deep.
    // (3-deep blew the 256-VGPR addressing cap -> spills; 2-deep fits.)
    f32x4 acc[4][7] = {};
    float4 xc0[4][2], xc1[4][2];     // stages t, t+1
    bf16x8 bc[7];
    {
        LOADX4(xc0, q * 8);          // t=0 (all in range)
        LOADX4(xc1, 32 + q * 8);     // t=1
        #pragma unroll
        for (int n = 0; n < 7; ++n) bc[n] = *(const bf16x8*)(wb + n * 512);
    }
    #pragma unroll 1
    for (int tt = 0; tt < NT / 2; ++tt) {
        const int t = tt * 2;
        // ---- phase A (iter t): prefetch x[t+2], B[t+1]; compute xc0 x bc
        float4 xn0[4][2];
        const int kkA = (t + 2) * 32 + q * 8;
        if (kkA + 8 <= DIN) LOADX4(xn0, kkA); else ZEROX4(xn0);
        const unsigned short* wA = wb + (t + 1) * (7 * 512);
        bf16x8 bn[7];
        #pragma unroll
        for (int n = 0; n < 7; ++n) bn[n] = *(const bf16x8*)(wA + n * 512);
        CVT_MFMA4(xc0, bc);

        // ---- phase B (iter t+1): prefetch x[t+3], B[t+2]; compute xc1 x bn
        float4 xn1[4][2];
        const int kkB = (t + 3) * 32 + q * 8;
        if (kkB + 8 <= DIN) LOADX4(xn1, kkB); else ZEROX4(xn1);
        const int tb2 = (t + 2 < NT) ? (t + 2) : (NT - 1);
        const unsigned short* wB = wb + tb2 * (7 * 512);
        #pragma unroll
        for (int n = 0; n < 7; ++n) bc[n] = *(const bf16x8*)(wB + n * 512);
        CVT_MFMA4(xc1, bn);

        // rotate x stages
        #pragma unroll
        for (int m = 0; m < 4; ++m) {
            xc0[m][0] = xn0[m][0]; xc0[m][1] = xn0[m][1];
            xc1[m][0] = xn1[m][0]; xc1[m][1] = xn1[m][1];
        }
    }

    // ---- zero-pad hs cols 112..127 (GEMM2 reads them; avoid NaN garbage)
    {
        uint4 z; z.x = z.y = z.z = z.w = 0;
        *(uint4*)&hs[tid][112] = z;
        *(uint4*)&hs[tid][120] = z;
    }

    // ---- bias + relu -> hs (bf16); freq partial from registers (no atomics)
    const bool lastBlk = (blockIdx.x == GRID1 - 1);
    #pragma unroll
    for (int n = 0; n < 7; ++n) {
        const int col = n * 16 + r16;
        const float bias = (col < DHID) ? b1[col] : 0.f;
        float cnt = 0.f;
        #pragma unroll
        for (int m = 0; m < 4; ++m)
            #pragma unroll
            for (int i = 0; i < 4; ++i) {
                float v = acc[m][n][i] + bias;
                v = v > 0.f ? v : 0.f;
                union { __bf16 h; unsigned short u; } cv;
                cv.h = (__bf16)v;
                hs[wave * 64 + m * 16 + q * 4 + i][col] = cv.u;
                // reference skips the globally-last row (65535)
                bool excl = lastBlk && (wave == 3) && (m == 3) && (q == 3) && (i == 3);
                cnt += (v > 0.f && !excl) ? 1.f : 0.f;
            }
        cnt += __shfl_xor(cnt, 16);   // reduce over q (lane = q*16 + r16)
        cnt += __shfl_xor(cnt, 32);
        if (q == 0) ((float*)logits)[wave * NP + col] = cnt;  // flat < 448, disjoint
    }
    __syncthreads();
    if (tid < NP) {
        float s = ((float*)logits)[0 * NP + tid] + ((float*)logits)[1 * NP + tid]
                + ((float*)logits)[2 * NP + tid] + ((float*)logits)[3 * NP + tid];
        part[(size_t)blockIdx.x * NP + tid] = s;
    }
    __syncthreads();   // logits scratch free before GEMM2 reuses it

    // ---- GEMM2 via MFMA: logits[256][16] = hs[256][128] @ w2t^T, K=128
    const unsigned short* w2t = wbuf + W2T_OFF;
    bf16x8 bv2[4];
    #pragma unroll
    for (int ks = 0; ks < 4; ++ks)
        bv2[ks] = *(const bf16x8*)(w2t + r16 * 128 + ks * 32 + q * 8);
    f32x4 acc2[4] = {};
    #pragma unroll
    for (int m = 0; m < 4; ++m)
        #pragma unroll
        for (int ks = 0; ks < 4; ++ks) {
            bf16x8 a2 = *(const bf16x8*)&hs[wave * 64 + m * 16 + r16][ks * 32 + q * 8];
            acc2[m] = __builtin_amdgcn_mfma_f32_16x16x32_bf16(a2, bv2[ks], acc2[m], 0, 0, 0);
        }
    const float bias2 = (r16 < DOUT) ? b2[r16] : 0.f;
    #pragma unroll
    for (int m = 0; m < 4; ++m)
        #pragma unroll
        for (int i = 0; i < 4; ++i)
            logits[wave * 64 + m * 16 + q * 4 + i][r16] = acc2[m][i] + bias2;
    __syncthreads();

    // ---- softmax: one thread per row (all 256 threads active)
    {
        float lg[DOUT];
        #pragma unroll
        for (int k = 0; k < DOUT; ++k) lg[k] = logits[tid][k];
        float mx = lg[0];
        #pragma unroll
        for (int k = 1; k < DOUT; ++k) mx = fmaxf(mx, lg[k]);
        float s = 0.f;
        #pragma unroll
        for (int k = 0; k < DOUT; ++k) { lg[k] = __expf(lg[k] - mx); s += lg[k]; }
        float inv = 1.f / s;
        float* o = outp + ((size_t)blockIdx.x * TM + tid) * DOUT;
        #pragma unroll
        for (int k = 0; k < DOUT; ++k) o[k] = lg[k] * inv;
    }

    // ---- completion counter: last block reduces part -> freq_out (no extra kernel)
    __threadfence();                                   // release part writes, device scope
    if (tid == 0) {
        unsigned old = atomicAdd(done, 1u);            // device-scope by default
        lastFlag = (old == GRID1 - 1) ? 1 : 0;
    }
    __syncthreads();
    if (lastFlag) {
        __threadfence();                               // acquire other blocks' part writes
        // 224 threads: col = tid%112, half = tid/112; each sums 128 blocks.
        if (tid < 2 * NP) {
            const int col  = tid % NP;
            const int half = tid / NP;
            const int b0   = half * (GRID1 / 2);
            float s0 = 0.f, s1 = 0.f, s2 = 0.f, s3 = 0.f;
            #pragma unroll 4
            for (int b = 0; b < GRID1 / 2; b += 4) {
                s0 += part[(size_t)(b0 + b + 0) * NP + col];
                s1 += part[(size_t)(b0 + b + 1) * NP + col];
                s2 += part[(size_t)(b0 + b + 2) * NP + col];
                s3 += part[(size_t)(b0 + b + 3) * NP + col];
            }
            red[half][col] = ((s0 + s1) + (s2 + s3));
        }
        __syncthreads();
        if (tid < DHID)
            freq_out[tid] = freq_in[tid] + (red[0][tid] + red[1][tid]);
    }
}

extern "C" void kernel_launch(void* const* d_in, const int* in_sizes, int n_in,
                              void* d_out, int out_size, void* d_ws, size_t ws_size,
                              hipStream_t stream) {
    const float* x    = (const float*)d_in[0];
    const float* W1   = (const float*)d_in[1];
    const float* b1   = (const float*)d_in[2];
    const float* freq = (const float*)d_in[3];
    const float* W2   = (const float*)d_in[4];
    const float* b2   = (const float*)d_in[5];
    float* outp     = (float*)d_out;
    float* freq_out = outp + (size_t)B_ROWS * DOUT;
    unsigned short* wbuf = (unsigned short*)d_ws;
    float* part     = (float*)((char*)d_ws + PART_OFF);   // 256*112*4 = 115 KB
    unsigned* done  = (unsigned*)((char*)d_ws + CNT_OFF);

    prep_kernel<<<(WBUF_ELEMS + 255) / 256, 256, 0, stream>>>(W1, W2, wbuf, done);
    fused_mlp9<<<GRID1, 256, 0, stream>>>(x, wbuf, b1, b2, freq, outp, freq_out, part, done);
}

// Round 11
// 51.776 us; speedup vs baseline: 1.5353x; 1.5140x over previous
//
#include <hip/hip_runtime.h>
#include <hip/hip_bf16.h>

// Problem constants
#define B_ROWS 65536
#define DIN    784
#define DHID   100
#define DOUT   10

#define NP     112                 // DHID padded to 7*16
#define NT     27                  // k-steps of 32 (864; slots 784.. zero pad; 27 = 9*3 phases)
#define W1T_ELEMS (NT * 7 * 512)   // 96768 bf16, fragment-order layout
#define W2T_OFF   W1T_ELEMS        // w2t: [16][128] bf16 = 2048
#define WBUF_ELEMS (W1T_ELEMS + 2048)
#define PART_OFF  ((((WBUF_ELEMS * 2) + 255) & ~255))   // byte offset of freq partials
#define TM     128                 // rows per block (4 waves x 32 rows)
#define GRID1  (B_ROWS / TM)       // 512 -> 2 blocks/CU, 2 waves/SIMD

typedef float  f32x4  __attribute__((ext_vector_type(4)));
typedef __bf16 bf16x8 __attribute__((ext_vector_type(8)));

__device__ inline unsigned short f2bf(float f) {
    unsigned int u = __builtin_bit_cast(unsigned int, f);
    u = (u + 0x7fffu + ((u >> 16) & 1u)) >> 16;   // RNE
    return (unsigned short)u;
}

// ---- prep: build fragment-order W1T + W2T (bf16, zero-padded).
// W1T: idx = ((t*7+n)*64 + lane)*8 + j holds W1[k = t*32+(lane>>4)*8+j][col = n*16+(lane&15)]
__global__ void prep_kernel(const float* __restrict__ W1,
                            const float* __restrict__ W2,
                            unsigned short* __restrict__ wbuf) {
    int idx = blockIdx.x * 256 + threadIdx.x;
    if (idx < W1T_ELEMS) {
        int s  = idx >> 9;          // fragment slot (t*7+n)
        int e  = idx & 511;
        int ln = e >> 3, j = e & 7;
        int n  = s % 7, t = s / 7;
        int k   = t * 32 + ((ln >> 4) << 3) + j;
        int col = n * 16 + (ln & 15);
        float v = (k < DIN && col < DHID) ? W1[k * DHID + col] : 0.f;
        wbuf[idx] = f2bf(v);
    } else if (idx < WBUF_ELEMS) {
        int j2 = idx - W1T_ELEMS;
        int r  = j2 >> 7;           // 0..15 (output col)
        int k  = j2 & 127;          // 0..127 (h col)
        float v = (r < DOUT && k < DHID) ? W2[k * DOUT + r] : 0.f;
        wbuf[idx] = f2bf(v);
    }
}

#define LOADX2(dst, kk)                                                         \
    do {                                                                        \
        _Pragma("unroll")                                                       \
        for (int m = 0; m < 2; ++m) {                                           \
            dst[m][0] = *(const float4*)(xp[m] + (kk));                         \
            dst[m][1] = *(const float4*)(xp[m] + (kk) + 4);                     \
        }                                                                       \
    } while (0)

#define ZEROX2(dst)                                                             \
    do {                                                                        \
        _Pragma("unroll")                                                       \
        for (int m = 0; m < 2; ++m)                                             \
            dst[m][0] = dst[m][1] = make_float4(0.f, 0.f, 0.f, 0.f);            \
    } while (0)

#define CVT_MFMA2(xc, bsrc)                                                     \
    do {                                                                        \
        bf16x8 av[2];                                                           \
        _Pragma("unroll")                                                       \
        for (int m = 0; m < 2; ++m) {                                           \
            av[m][0] = (__bf16)xc[m][0].x; av[m][1] = (__bf16)xc[m][0].y;       \
            av[m][2] = (__bf16)xc[m][0].z; av[m][3] = (__bf16)xc[m][0].w;       \
            av[m][4] = (__bf16)xc[m][1].x; av[m][5] = (__bf16)xc[m][1].y;       \
            av[m][6] = (__bf16)xc[m][1].z; av[m][7] = (__bf16)xc[m][1].w;       \
        }                                                                       \
        _Pragma("unroll")                                                       \
        for (int n = 0; n < 7; ++n)                                             \
            _Pragma("unroll")                                                   \
            for (int m = 0; m < 2; ++m)                                         \
                acc[m][n] = __builtin_amdgcn_mfma_f32_16x16x32_bf16(            \
                    av[m], bsrc[n], acc[m][n], 0, 0, 0);                        \
    } while (0)

// one pipeline phase: consume (xs,bs) for k-step t; refill slot with t+3
#define PHASE(xs, bs, t)                                                        \
    do {                                                                        \
        float4 xn[2][2];                                                        \
        const int kk = ((t) + 3) * 32 + q * 8;                                  \
        if (kk + 8 <= DIN) LOADX2(xn, kk); else ZEROX2(xn);                     \
        const int tb = ((t) + 3 < NT) ? (t) + 3 : NT - 1;                       \
        const unsigned short* wp = wb + tb * (7 * 512);                         \
        bf16x8 bn[7];                                                           \
        _Pragma("unroll")                                                       \
        for (int n = 0; n < 7; ++n) bn[n] = *(const bf16x8*)(wp + n * 512);     \
        CVT_MFMA2(xs, bs);                                                      \
        _Pragma("unroll")                                                       \
        for (int m = 0; m < 2; ++m) { xs[m][0] = xn[m][0]; xs[m][1] = xn[m][1]; } \
        _Pragma("unroll")                                                       \
        for (int n = 0; n < 7; ++n) bs[n] = bn[n];                              \
    } while (0)

__global__ __launch_bounds__(256, 2)
void fused_mlp10(const float* __restrict__ x,
                 const unsigned short* __restrict__ wbuf,
                 const float* __restrict__ b1,
                 const float* __restrict__ b2,
                 float* __restrict__ outp,
                 float* __restrict__ part) {
    __shared__ unsigned short hs[TM][128];   // 32 KB bf16 h tile (cols 112..127 zeroed)
    __shared__ float logits[TM][16];         // 8 KB; reused: freq scratch then logits

    const int tid  = threadIdx.x;
    const int lane = tid & 63;
    const int wave = tid >> 6;       // 0..3, owns rows wave*32 .. +31
    const int r16  = lane & 15;
    const int q    = lane >> 4;      // 0..3

    const float* xp[2];
    #pragma unroll
    for (int m = 0; m < 2; ++m)
        xp[m] = x + ((size_t)blockIdx.x * TM + wave * 32 + m * 16 + r16) * DIN;
    const unsigned short* wb = wbuf + lane * 8;

    // ---- GEMM1: 32 rows/wave, x and B pipelined 3 deep (static 3-slot rotation).
    // m=2 keeps total VGPR ~220 < 256 addressing cap (m=4 version spilled, R9).
    f32x4 acc[2][7] = {};
    float4 xs0[2][2], xs1[2][2], xs2[2][2];
    bf16x8 bs0[7], bs1[7], bs2[7];
    {
        LOADX2(xs0, 0 * 32 + q * 8);
        LOADX2(xs1, 1 * 32 + q * 8);
        LOADX2(xs2, 2 * 32 + q * 8);
        #pragma unroll
        for (int n = 0; n < 7; ++n) {
            bs0[n] = *(const bf16x8*)(wb + 0 * 3584 + n * 512);
            bs1[n] = *(const bf16x8*)(wb + 1 * 3584 + n * 512);
            bs2[n] = *(const bf16x8*)(wb + 2 * 3584 + n * 512);
        }
    }
    #pragma unroll 1
    for (int tt = 0; tt < NT / 3; ++tt) {
        const int t = tt * 3;
        PHASE(xs0, bs0, t);
        PHASE(xs1, bs1, t + 1);
        PHASE(xs2, bs2, t + 2);
    }

    // ---- zero-pad hs cols 112..127 (GEMM2 reads them; avoid NaN garbage)
    {
        int r = tid >> 1, cc = (tid & 1) << 3;        // 16 B per thread
        uint4 z; z.x = z.y = z.z = z.w = 0;
        *(uint4*)&hs[r][112 + cc] = z;
    }

    // ---- bias + relu -> hs (bf16); freq partial from registers (no atomics)
    const bool lastBlk = (blockIdx.x == GRID1 - 1);
    #pragma unroll
    for (int n = 0; n < 7; ++n) {
        const int col = n * 16 + r16;
        const float bias = (col < DHID) ? b1[col] : 0.f;
        float cnt = 0.f;
        #pragma unroll
        for (int m = 0; m < 2; ++m)
            #pragma unroll
            for (int i = 0; i < 4; ++i) {
                float v = acc[m][n][i] + bias;
                v = v > 0.f ? v : 0.f;
                union { __bf16 h; unsigned short u; } cv;
                cv.h = (__bf16)v;
                hs[wave * 32 + m * 16 + q * 4 + i][col] = cv.u;
                // reference skips the globally-last row (65535)
                bool excl = lastBlk && (wave == 3) && (m == 1) && (q == 3) && (i == 3);
                cnt += (v > 0.f && !excl) ? 1.f : 0.f;
            }
        cnt += __shfl_xor(cnt, 16);   // reduce over q (lane = q*16 + r16)
        cnt += __shfl_xor(cnt, 32);
        if (q == 0) ((float*)logits)[wave * NP + col] = cnt;  // flat < 448, disjoint
    }
    __syncthreads();
    if (tid < NP) {
        float s = ((float*)logits)[0 * NP + tid] + ((float*)logits)[1 * NP + tid]
                + ((float*)logits)[2 * NP + tid] + ((float*)logits)[3 * NP + tid];
        part[(size_t)blockIdx.x * NP + tid] = s;
    }
    __syncthreads();   // logits scratch free before GEMM2 reuses it

    // ---- GEMM2 via MFMA: logits[128][16] = hs[128][128] @ w2t^T, K=128
    const unsigned short* w2t = wbuf + W2T_OFF;
    bf16x8 bv2[4];
    #pragma unroll
    for (int ks = 0; ks < 4; ++ks)
        bv2[ks] = *(const bf16x8*)(w2t + r16 * 128 + ks * 32 + q * 8);
    f32x4 acc2[2] = {};
    #pragma unroll
    for (int m = 0; m < 2; ++m)
        #pragma unroll
        for (int ks = 0; ks < 4; ++ks) {
            bf16x8 a2 = *(const bf16x8*)&hs[wave * 32 + m * 16 + r16][ks * 32 + q * 8];
            acc2[m] = __builtin_amdgcn_mfma_f32_16x16x32_bf16(a2, bv2[ks], acc2[m], 0, 0, 0);
        }
    const float bias2 = (r16 < DOUT) ? b2[r16] : 0.f;
    #pragma unroll
    for (int m = 0; m < 2; ++m)
        #pragma unroll
        for (int i = 0; i < 4; ++i)
            logits[wave * 32 + m * 16 + q * 4 + i][r16] = acc2[m][i] + bias2;
    __syncthreads();

    // ---- softmax: one thread per row
    if (tid < TM) {
        float lg[DOUT];
        #pragma unroll
        for (int k = 0; k < DOUT; ++k) lg[k] = logits[tid][k];
        float mx = lg[0];
        #pragma unroll
        for (int k = 1; k < DOUT; ++k) mx = fmaxf(mx, lg[k]);
        float s = 0.f;
        #pragma unroll
        for (int k = 0; k < DOUT; ++k) { lg[k] = __expf(lg[k] - mx); s += lg[k]; }
        float inv = 1.f / s;
        float* o = outp + ((size_t)blockIdx.x * TM + tid) * DOUT;
        #pragma unroll
        for (int k = 0; k < DOUT; ++k) o[k] = lg[k] * inv;
    }
}

// ---- final freq reduction: freq_out[j] = freq_in[j] + sum_b part[b][j]
__global__ void freq_reduce(const float* __restrict__ part,
                            const float* __restrict__ freq_in,
                            float* __restrict__ freq_out) {
    __shared__ float ws[4];
    const int j = blockIdx.x;        // 0..DHID-1
    const int tid = threadIdx.x;
    float s = 0.f;
    for (int b = tid; b < GRID1; b += 256) s += part[(size_t)b * NP + j];
    #pragma unroll
    for (int d = 1; d < 64; d <<= 1) s += __shfl_xor(s, d);
    if ((tid & 63) == 0) ws[tid >> 6] = s;
    __syncthreads();
    if (tid == 0) freq_out[j] = freq_in[j] + ws[0] + ws[1] + ws[2] + ws[3];
}

extern "C" void kernel_launch(void* const* d_in, const int* in_sizes, int n_in,
                              void* d_out, int out_size, void* d_ws, size_t ws_size,
                              hipStream_t stream) {
    const float* x    = (const float*)d_in[0];
    const float* W1   = (const float*)d_in[1];
    const float* b1   = (const float*)d_in[2];
    const float* freq = (const float*)d_in[3];
    const float* W2   = (const float*)d_in[4];
    const float* b2   = (const float*)d_in[5];
    float* outp     = (float*)d_out;
    float* freq_out = outp + (size_t)B_ROWS * DOUT;
    unsigned short* wbuf = (unsigned short*)d_ws;
    float* part = (float*)((char*)d_ws + PART_OFF);   // 512*112*4 = 229 KB

    prep_kernel<<<(WBUF_ELEMS + 255) / 256, 256, 0, stream>>>(W1, W2, wbuf);
    fused_mlp10<<<GRID1, 256, 0, stream>>>(x, wbuf, b1, b2, outp, part);
    freq_reduce<<<DHID, 256, 0, stream>>>(part, freq, freq_out);
}

// Round 12
// 49.002 us; speedup vs baseline: 1.6222x; 1.0566x over previous
//
#include <hip/hip_runtime.h>
#include <hip/hip_bf16.h>

// Problem constants
#define B_ROWS 65536
#define DIN    784
#define DHID   100
#define DOUT   10

#define NP     112                 // DHID padded to 7*16
#define NT     27                  // k-steps of 32 (864; slots 784.. zero pad; 27 = 9*3)
#define W1T_ELEMS (NT * 7 * 512)   // 96768 bf16, fragment-order layout
#define W2T_OFF   W1T_ELEMS        // w2t: [16][128] bf16 = 2048
#define WBUF_ELEMS (W1T_ELEMS + 2048)
#define PART_OFF  ((((WBUF_ELEMS * 2) + 255) & ~255))   // byte offset of freq partials
#define TM     256                 // rows per block (4 waves x 64 rows)
#define GRID1  (B_ROWS / TM)       // 256 -> 1 block/CU, 1 wave/SIMD

typedef float  f32x4  __attribute__((ext_vector_type(4)));
typedef __bf16 bf16x8 __attribute__((ext_vector_type(8)));

__device__ inline unsigned short f2bf(float f) {
    unsigned int u = __builtin_bit_cast(unsigned int, f);
    u = (u + 0x7fffu + ((u >> 16) & 1u)) >> 16;   // RNE
    return (unsigned short)u;
}

// ---- prep: build fragment-order W1T + W2T (bf16, zero-padded).
// W1T: idx = ((t*7+n)*64 + lane)*8 + j holds W1[k = t*32+(lane>>4)*8+j][col = n*16+(lane&15)]
__global__ void prep_kernel(const float* __restrict__ W1,
                            const float* __restrict__ W2,
                            unsigned short* __restrict__ wbuf) {
    int idx = blockIdx.x * 256 + threadIdx.x;
    if (idx < W1T_ELEMS) {
        int s  = idx >> 9;          // fragment slot (t*7+n)
        int e  = idx & 511;
        int ln = e >> 3, j = e & 7;
        int n  = s % 7, t = s / 7;
        int k   = t * 32 + ((ln >> 4) << 3) + j;
        int col = n * 16 + (ln & 15);
        float v = (k < DIN && col < DHID) ? W1[k * DHID + col] : 0.f;
        wbuf[idx] = f2bf(v);
    } else if (idx < WBUF_ELEMS) {
        int j2 = idx - W1T_ELEMS;
        int r  = j2 >> 7;           // 0..15 (output col)
        int k  = j2 & 127;          // 0..127 (h col)
        float v = (r < DOUT && k < DHID) ? W2[k * DOUT + r] : 0.f;
        wbuf[idx] = f2bf(v);
    }
}

#define LOADX4(dst, kk)                                                         \
    do {                                                                        \
        _Pragma("unroll")                                                       \
        for (int m = 0; m < 4; ++m) {                                           \
            dst[m][0] = *(const float4*)(xp[m] + (kk));                         \
            dst[m][1] = *(const float4*)(xp[m] + (kk) + 4);                     \
        }                                                                       \
    } while (0)

#define ZEROX4(dst)                                                             \
    do {                                                                        \
        _Pragma("unroll")                                                       \
        for (int m = 0; m < 4; ++m)                                             \
            dst[m][0] = dst[m][1] = make_float4(0.f, 0.f, 0.f, 0.f);            \
    } while (0)

// one phase: B(t) loaded fresh at phase head (L1-hot, ~100cy cover);
// x slot consumed was loaded 3 phases ago (~750cy cover); refill with t+3.
#define PHASE(xs, t)                                                            \
    do {                                                                        \
        const unsigned short* wp = wb + (t) * (7 * 512);                        \
        bf16x8 bcur[7];                                                         \
        _Pragma("unroll")                                                       \
        for (int n = 0; n < 7; ++n) bcur[n] = *(const bf16x8*)(wp + n * 512);   \
        float4 xn[4][2];                                                        \
        const int kk = ((t) + 3) * 32 + q * 8;                                  \
        if (kk + 8 <= DIN) LOADX4(xn, kk); else ZEROX4(xn);                     \
        bf16x8 av[4];                                                           \
        _Pragma("unroll")                                                       \
        for (int m = 0; m < 4; ++m) {                                           \
            av[m][0] = (__bf16)xs[m][0].x; av[m][1] = (__bf16)xs[m][0].y;       \
            av[m][2] = (__bf16)xs[m][0].z; av[m][3] = (__bf16)xs[m][0].w;       \
            av[m][4] = (__bf16)xs[m][1].x; av[m][5] = (__bf16)xs[m][1].y;       \
            av[m][6] = (__bf16)xs[m][1].z; av[m][7] = (__bf16)xs[m][1].w;       \
        }                                                                       \
        _Pragma("unroll")                                                       \
        for (int n = 0; n < 7; ++n)                                             \
            _Pragma("unroll")                                                   \
            for (int m = 0; m < 4; ++m)                                         \
                acc[m][n] = __builtin_amdgcn_mfma_f32_16x16x32_bf16(            \
                    av[m], bcur[n], acc[m][n], 0, 0, 0);                        \
        _Pragma("unroll")                                                       \
        for (int m = 0; m < 4; ++m) { xs[m][0] = xn[m][0]; xs[m][1] = xn[m][1]; } \
    } while (0)

__global__ __launch_bounds__(256, 1)
void fused_mlp11(const float* __restrict__ x,
                 const unsigned short* __restrict__ wbuf,
                 const float* __restrict__ b1,
                 const float* __restrict__ b2,
                 float* __restrict__ outp,
                 float* __restrict__ part) {
    __shared__ unsigned short hs[TM][128];   // 64 KB bf16 h tile (cols 112..127 zeroed)
    __shared__ float logits[TM][16];         // 16 KB; reused: freq scratch then logits

    const int tid  = threadIdx.x;
    const int lane = tid & 63;
    const int wave = tid >> 6;       // 0..3, owns rows wave*64 .. +63
    const int r16  = lane & 15;
    const int q    = lane >> 4;      // 0..3

    const float* xp[4];
    #pragma unroll
    for (int m = 0; m < 4; ++m)
        xp[m] = x + ((size_t)blockIdx.x * TM + wave * 64 + m * 16 + r16) * DIN;
    const unsigned short* wb = wbuf + lane * 8;

    // ---- GEMM1: 64 rows/wave; x 3-deep (3 static slots), B 0-deep (L1-hot).
    // VGPR: acc 112 + x 96 + B 28 + misc -> fits under the 256 addressing cap.
    f32x4 acc[4][7] = {};
    float4 xs0[4][2], xs1[4][2], xs2[4][2];
    {
        LOADX4(xs0, 0 * 32 + q * 8);
        LOADX4(xs1, 1 * 32 + q * 8);
        LOADX4(xs2, 2 * 32 + q * 8);
    }
    #pragma unroll 1
    for (int tt = 0; tt < NT / 3; ++tt) {
        const int t = tt * 3;
        PHASE(xs0, t);
        PHASE(xs1, t + 1);
        PHASE(xs2, t + 2);
    }

    // ---- zero-pad hs cols 112..127 (GEMM2 reads them; avoid NaN garbage)
    {
        uint4 z; z.x = z.y = z.z = z.w = 0;
        *(uint4*)&hs[tid][112] = z;
        *(uint4*)&hs[tid][120] = z;
    }

    // ---- bias + relu -> hs (bf16); freq partial from registers (no atomics)
    const bool lastBlk = (blockIdx.x == GRID1 - 1);
    #pragma unroll
    for (int n = 0; n < 7; ++n) {
        const int col = n * 16 + r16;
        const float bias = (col < DHID) ? b1[col] : 0.f;
        float cnt = 0.f;
        #pragma unroll
        for (int m = 0; m < 4; ++m)
            #pragma unroll
            for (int i = 0; i < 4; ++i) {
                float v = acc[m][n][i] + bias;
                v = v > 0.f ? v : 0.f;
                union { __bf16 h; unsigned short u; } cv;
                cv.h = (__bf16)v;
                hs[wave * 64 + m * 16 + q * 4 + i][col] = cv.u;
                // reference skips the globally-last row (65535)
                bool excl = lastBlk && (wave == 3) && (m == 3) && (q == 3) && (i == 3);
                cnt += (v > 0.f && !excl) ? 1.f : 0.f;
            }
        cnt += __shfl_xor(cnt, 16);   // reduce over q (lane = q*16 + r16)
        cnt += __shfl_xor(cnt, 32);
        if (q == 0) ((float*)logits)[wave * NP + col] = cnt;  // flat < 448, disjoint
    }
    __syncthreads();
    if (tid < NP) {
        float s = ((float*)logits)[0 * NP + tid] + ((float*)logits)[1 * NP + tid]
                + ((float*)logits)[2 * NP + tid] + ((float*)logits)[3 * NP + tid];
        part[(size_t)blockIdx.x * NP + tid] = s;
    }
    __syncthreads();   // logits scratch free before GEMM2 reuses it

    // ---- GEMM2 via MFMA: logits[256][16] = hs[256][128] @ w2t^T, K=128
    const unsigned short* w2t = wbuf + W2T_OFF;
    bf16x8 bv2[4];
    #pragma unroll
    for (int ks = 0; ks < 4; ++ks)
        bv2[ks] = *(const bf16x8*)(w2t + r16 * 128 + ks * 32 + q * 8);
    f32x4 acc2[4] = {};
    #pragma unroll
    for (int m = 0; m < 4; ++m)
        #pragma unroll
        for (int ks = 0; ks < 4; ++ks) {
            bf16x8 a2 = *(const bf16x8*)&hs[wave * 64 + m * 16 + r16][ks * 32 + q * 8];
            acc2[m] = __builtin_amdgcn_mfma_f32_16x16x32_bf16(a2, bv2[ks], acc2[m], 0, 0, 0);
        }
    const float bias2 = (r16 < DOUT) ? b2[r16] : 0.f;
    #pragma unroll
    for (int m = 0; m < 4; ++m)
        #pragma unroll
        for (int i = 0; i < 4; ++i)
            logits[wave * 64 + m * 16 + q * 4 + i][r16] = acc2[m][i] + bias2;
    __syncthreads();

    // ---- softmax: one thread per row (all 256 threads active)
    {
        float lg[DOUT];
        #pragma unroll
        for (int k = 0; k < DOUT; ++k) lg[k] = logits[tid][k];
        float mx = lg[0];
        #pragma unroll
        for (int k = 1; k < DOUT; ++k) mx = fmaxf(mx, lg[k]);
        float s = 0.f;
        #pragma unroll
        for (int k = 0; k < DOUT; ++k) { lg[k] = __expf(lg[k] - mx); s += lg[k]; }
        float inv = 1.f / s;
        float* o = outp + ((size_t)blockIdx.x * TM + tid) * DOUT;
        #pragma unroll
        for (int k = 0; k < DOUT; ++k) o[k] = lg[k] * inv;
    }
}

// ---- final freq reduction: freq_out[j] = freq_in[j] + sum_b part[b][j]
__global__ void freq_reduce(const float* __restrict__ part,
                            const float* __restrict__ freq_in,
                            float* __restrict__ freq_out) {
    __shared__ float ws[4];
    const int j = blockIdx.x;        // 0..DHID-1
    const int tid = threadIdx.x;
    float s = 0.f;
    for (int b = tid; b < GRID1; b += 256) s += part[(size_t)b * NP + j];
    #pragma unroll
    for (int d = 1; d < 64; d <<= 1) s += __shfl_xor(s, d);
    if ((tid & 63) == 0) ws[tid >> 6] = s;
    __syncthreads();
    if (tid == 0) freq_out[j] = freq_in[j] + ws[0] + ws[1] + ws[2] + ws[3];
}

extern "C" void kernel_launch(void* const* d_in, const int* in_sizes, int n_in,
                              void* d_out, int out_size, void* d_ws, size_t ws_size,
                              hipStream_t stream) {
    const float* x    = (const float*)d_in[0];
    const float* W1   = (const float*)d_in[1];
    const float* b1   = (const float*)d_in[2];
    const float* freq = (const float*)d_in[3];
    const float* W2   = (const float*)d_in[4];
    const float* b2   = (const float*)d_in[5];
    float* outp     = (float*)d_out;
    float* freq_out = outp + (size_t)B_ROWS * DOUT;
    unsigned short* wbuf = (unsigned short*)d_ws;
    float* part = (float*)((char*)d_ws + PART_OFF);   // 256*112*4 = 115 KB

    prep_kernel<<<(WBUF_ELEMS + 255) / 256, 256, 0, stream>>>(W1, W2, wbuf);
    fused_mlp11<<<GRID1, 256, 0, stream>>>(x, wbuf, b1, b2, outp, part);
    freq_reduce<<<DHID, 256, 0, stream>>>(part, freq, freq_out);
}

// Round 13
// 48.995 us; speedup vs baseline: 1.6224x; 1.0001x over previous
//
#include <hip/hip_runtime.h>
#include <hip/hip_bf16.h>

// Problem constants
#define B_ROWS 65536
#define DIN    784
#define DHID   100
#define DOUT   10

#define NP     112                 // DHID padded to 7*16
#define NT     25                  // k-steps of 32 (800; k 784.. zero-padded in W1T)
#define W1T_ELEMS (NT * 7 * 512)   // 89600 bf16, fragment-order layout
#define W2T_OFF   W1T_ELEMS        // w2t: [16][128] bf16 = 2048
#define WBUF_ELEMS (W1T_ELEMS + 2048)
#define PART_OFF  ((((WBUF_ELEMS * 2) + 255) & ~255))   // byte offset of freq partials
#define TM     128                 // rows per block (4 waves x 32 rows)
#define GRID1  (B_ROWS / TM)       // 512 -> 2 blocks/CU (barrier overlap between blocks)

typedef float  f32x4  __attribute__((ext_vector_type(4)));
typedef __bf16 bf16x8 __attribute__((ext_vector_type(8)));

__device__ inline unsigned short f2bf(float f) {
    unsigned int u = __builtin_bit_cast(unsigned int, f);
    u = (u + 0x7fffu + ((u >> 16) & 1u)) >> 16;   // RNE
    return (unsigned short)u;
}

// ---- prep: build fragment-order W1T + W2T (bf16, zero-padded).
// W1T: idx = ((t*7+n)*64 + lane)*8 + j holds W1[k = t*32+(lane>>4)*8+j][col = n*16+(lane&15)]
__global__ void prep_kernel(const float* __restrict__ W1,
                            const float* __restrict__ W2,
                            unsigned short* __restrict__ wbuf) {
    int idx = blockIdx.x * 256 + threadIdx.x;
    if (idx < W1T_ELEMS) {
        int s  = idx >> 9;          // fragment slot (t*7+n)
        int e  = idx & 511;
        int ln = e >> 3, j = e & 7;
        int n  = s % 7, t = s / 7;
        int k   = t * 32 + ((ln >> 4) << 3) + j;
        int col = n * 16 + (ln & 15);
        float v = (k < DIN && col < DHID) ? W1[k * DHID + col] : 0.f;
        wbuf[idx] = f2bf(v);
    } else if (idx < WBUF_ELEMS) {
        int j2 = idx - W1T_ELEMS;
        int r  = j2 >> 7;           // 0..15 (output col)
        int k  = j2 & 127;          // 0..127 (h col)
        float v = (r < DOUT && k < DHID) ? W2[k * DOUT + r] : 0.f;
        wbuf[idx] = f2bf(v);
    }
}

// global_load_lds: 16 B per lane, dest = wave-uniform LDS base + lane*16 (HW).
#define GLD_LDS16(srcp, ldsp)                                                   \
    __builtin_amdgcn_global_load_lds(                                           \
        (const __attribute__((address_space(1))) void*)(srcp),                  \
        (__attribute__((address_space(3))) void*)(ldsp), 16, 0, 0)

// Stage x k-tile t1 (128 rows x 32 f32) into xstage[bsel], XOR-swizzled source:
// LDS is LINEAR in granule G (16 B units); granule G holds row = G>>3,
// phys-granule pg = G&7, logical granule lg = pg ^ (row&7)  ->  x[row][lg*4..+3].
// Reads undo the XOR, making ds_read_b128 2-way-conflict (free) instead of 16-way.
#define DMA_TILE(t1, bsel)                                                      \
    do {                                                                        \
        _Pragma("unroll")                                                       \
        for (int c = 0; c < 4; ++c) {                                           \
            int G   = (wave * 4 + c) * 64 + lane;                               \
            int row = G >> 3;                                                   \
            int lg  = (G & 7) ^ (row & 7);                                      \
            int gb  = (t1) * 128 + lg * 16;      /* byte offset within row */   \
            gb = (gb + 16 <= DIN * 4) ? gb : 0;  /* clamp: junk x B-pad(0)=0 */ \
            const float* srcp = xblk + row * DIN + (gb >> 2);                   \
            float* dstp = &xstage[bsel][(wave * 4 + c) * 256];                  \
            GLD_LDS16(srcp, dstp);                                              \
        }                                                                       \
    } while (0)

__global__ __launch_bounds__(256, 2)
void fused_mlp12(const float* __restrict__ x,
                 const unsigned short* __restrict__ wbuf,
                 const float* __restrict__ b1,
                 const float* __restrict__ b2,
                 float* __restrict__ outp,
                 float* __restrict__ part) {
    __shared__ float xstage[2][128 * 32];    // 32 KB double-buffered x k-tile (swizzled)
    __shared__ unsigned short hs[TM][128];   // 32 KB bf16 h tile (cols 112..127 zeroed)
    __shared__ float logits[TM][16];         // 8 KB; reused: freq scratch then logits

    const int tid  = threadIdx.x;
    const int lane = tid & 63;
    const int wave = tid >> 6;       // 0..3, owns rows wave*32 .. +31
    const int r16  = lane & 15;
    const int q    = lane >> 4;      // 0..3

    const float* xblk = x + (size_t)blockIdx.x * TM * DIN;
    const unsigned short* wb = wbuf + lane * 8;

    // ---- GEMM1: x staged global->LDS via DMA queue (deep MLP without VGPRs);
    // B 1-deep in registers (R7 scheme). One barrier per k-step; 2 blocks/CU
    // cover each other's barrier drain.
    f32x4 acc[2][7] = {};
    bf16x8 bc[7];
    DMA_TILE(0, 0);
    #pragma unroll
    for (int n = 0; n < 7; ++n) bc[n] = *(const bf16x8*)(wb + n * 512);
    __syncthreads();   // tile 0 landed (vmcnt drain)

    #pragma unroll 1
    for (int t = 0; t < NT; ++t) {
        if (t + 1 < NT) DMA_TILE(t + 1, (t + 1) & 1);   // overlaps this phase
        const int tb = (t + 1 < NT) ? (t + 1) : (NT - 1);
        const unsigned short* wp = wb + tb * 3584;
        bf16x8 bn[7];
        #pragma unroll
        for (int n = 0; n < 7; ++n) bn[n] = *(const bf16x8*)(wp + n * 512);

        const float* xs = xstage[t & 1];
        bf16x8 av[2];
        #pragma unroll
        for (int m = 0; m < 2; ++m) {
            const int row = wave * 32 + m * 16 + r16;
            const int sw  = row & 7;
            float4 a0 = *(const float4*)&xs[row * 32 + ((((q << 1) | 0) ^ sw) << 2)];
            float4 a1 = *(const float4*)&xs[row * 32 + ((((q << 1) | 1) ^ sw) << 2)];
            av[m][0] = (__bf16)a0.x; av[m][1] = (__bf16)a0.y;
            av[m][2] = (__bf16)a0.z; av[m][3] = (__bf16)a0.w;
            av[m][4] = (__bf16)a1.x; av[m][5] = (__bf16)a1.y;
            av[m][6] = (__bf16)a1.z; av[m][7] = (__bf16)a1.w;
        }
        #pragma unroll
        for (int n = 0; n < 7; ++n)
            #pragma unroll
            for (int m = 0; m < 2; ++m)
                acc[m][n] = __builtin_amdgcn_mfma_f32_16x16x32_bf16(av[m], bc[n], acc[m][n], 0, 0, 0);
        #pragma unroll
        for (int n = 0; n < 7; ++n) bc[n] = bn[n];
        __syncthreads();   // reads of buf[t&1] done; DMA(t+1) landed
    }

    // ---- zero-pad hs cols 112..127 (GEMM2 reads them; avoid NaN garbage)
    {
        int r = tid >> 1, cc = (tid & 1) << 3;        // 16 B per thread
        uint4 z; z.x = z.y = z.z = z.w = 0;
        *(uint4*)&hs[r][112 + cc] = z;
    }

    // ---- bias + relu -> hs (bf16); freq partial from registers (no atomics)
    const bool lastBlk = (blockIdx.x == GRID1 - 1);
    #pragma unroll
    for (int n = 0; n < 7; ++n) {
        const int col = n * 16 + r16;
        const float bias = (col < DHID) ? b1[col] : 0.f;
        float cnt = 0.f;
        #pragma unroll
        for (int m = 0; m < 2; ++m)
            #pragma unroll
            for (int i = 0; i < 4; ++i) {
                float v = acc[m][n][i] + bias;
                v = v > 0.f ? v : 0.f;
                union { __bf16 h; unsigned short u; } cv;
                cv.h = (__bf16)v;
                hs[wave * 32 + m * 16 + q * 4 + i][col] = cv.u;
                // reference skips the globally-last row (65535)
                bool excl = lastBlk && (wave == 3) && (m == 1) && (q == 3) && (i == 3);
                cnt += (v > 0.f && !excl) ? 1.f : 0.f;
            }
        cnt += __shfl_xor(cnt, 16);   // reduce over q (lane = q*16 + r16)
        cnt += __shfl_xor(cnt, 32);
        if (q == 0) ((float*)logits)[wave * NP + col] = cnt;  // flat < 448, disjoint
    }
    __syncthreads();
    if (tid < NP) {
        float s = ((float*)logits)[0 * NP + tid] + ((float*)logits)[1 * NP + tid]
                + ((float*)logits)[2 * NP + tid] + ((float*)logits)[3 * NP + tid];
        part[(size_t)blockIdx.x * NP + tid] = s;
    }
    __syncthreads();   // logits scratch free before GEMM2 reuses it

    // ---- GEMM2 via MFMA: logits[128][16] = hs[128][128] @ w2t^T, K=128
    const unsigned short* w2t = wbuf + W2T_OFF;
    bf16x8 bv2[4];
    #pragma unroll
    for (int ks = 0; ks < 4; ++ks)
        bv2[ks] = *(const bf16x8*)(w2t + r16 * 128 + ks * 32 + q * 8);
    f32x4 acc2[2] = {};
    #pragma unroll
    for (int m = 0; m < 2; ++m)
        #pragma unroll
        for (int ks = 0; ks < 4; ++ks) {
            bf16x8 a2 = *(const bf16x8*)&hs[wave * 32 + m * 16 + r16][ks * 32 + q * 8];
            acc2[m] = __builtin_amdgcn_mfma_f32_16x16x32_bf16(a2, bv2[ks], acc2[m], 0, 0, 0);
        }
    const float bias2 = (r16 < DOUT) ? b2[r16] : 0.f;
    #pragma unroll
    for (int m = 0; m < 2; ++m)
        #pragma unroll
        for (int i = 0; i < 4; ++i)
            logits[wave * 32 + m * 16 + q * 4 + i][r16] = acc2[m][i] + bias2;
    __syncthreads();

    // ---- softmax: one thread per row
    if (tid < TM) {
        float lg[DOUT];
        #pragma unroll
        for (int k = 0; k < DOUT; ++k) lg[k] = logits[tid][k];
        float mx = lg[0];
        #pragma unroll
        for (int k = 1; k < DOUT; ++k) mx = fmaxf(mx, lg[k]);
        float s = 0.f;
        #pragma unroll
        for (int k = 0; k < DOUT; ++k) { lg[k] = __expf(lg[k] - mx); s += lg[k]; }
        float inv = 1.f / s;
        float* o = outp + ((size_t)blockIdx.x * TM + tid) * DOUT;
        #pragma unroll
        for (int k = 0; k < DOUT; ++k) o[k] = lg[k] * inv;
    }
}

// ---- final freq reduction: freq_out[j] = freq_in[j] + sum_b part[b][j]
__global__ void freq_reduce(const float* __restrict__ part,
                            const float* __restrict__ freq_in,
                            float* __restrict__ freq_out) {
    __shared__ float ws[4];
    const int j = blockIdx.x;        // 0..DHID-1
    const int tid = threadIdx.x;
    float s = 0.f;
    for (int b = tid; b < GRID1; b += 256) s += part[(size_t)b * NP + j];
    #pragma unroll
    for (int d = 1; d < 64; d <<= 1) s += __shfl_xor(s, d);
    if ((tid & 63) == 0) ws[tid >> 6] = s;
    __syncthreads();
    if (tid == 0) freq_out[j] = freq_in[j] + ws[0] + ws[1] + ws[2] + ws[3];
}

extern "C" void kernel_launch(void* const* d_in, const int* in_sizes, int n_in,
                              void* d_out, int out_size, void* d_ws, size_t ws_size,
                              hipStream_t stream) {
    const float* x    = (const float*)d_in[0];
    const float* W1   = (const float*)d_in[1];
    const float* b1   = (const float*)d_in[2];
    const float* freq = (const float*)d_in[3];
    const float* W2   = (const float*)d_in[4];
    const float* b2   = (const float*)d_in[5];
    float* outp     = (float*)d_out;
    float* freq_out = outp + (size_t)B_ROWS * DOUT;
    unsigned short* wbuf = (unsigned short*)d_ws;
    float* part = (float*)((char*)d_ws + PART_OFF);   // 512*112*4 = 229 KB

    prep_kernel<<<(WBUF_ELEMS + 255) / 256, 256, 0, stream>>>(W1, W2, wbuf);
    fused_mlp12<<<GRID1, 256, 0, stream>>>(x, wbuf, b1, b2, outp, part);
    freq_reduce<<<DHID, 256, 0, stream>>>(part, freq, freq_out);
}